// Round 4
// baseline (158.958 us; speedup 1.0000x reference)
//
#include <hip/hip_runtime.h>
#include <hip/hip_bf16.h>

// Problem constants
#define N_SRC 100000
#define N_MID 20000
#define N_OUT 5000
#define E_1   20000
#define E_2   20000
#define NCHUNK 33      // 32 W chunks + 1 bias chunk
#define NSPLIT 5       // chunk ranges (s*33/5, (s+1)*33/5): {6,7,6,7,7}
#define EBLK   128     // edges per block tile (2 M-tiles of 16 per wave)
#define NBLK   157     // ceil(20000/128)
#define EPAD   (NBLK*EBLK)   // 20096
#define MAXDEG 32      // slot table stride (Poisson(4) tail: P(deg>=32) ~ 1e-20)

#define PREP_N      (2*NCHUNK*512)            // 33792 prep work items
#define PREP_BLKS   ((PREP_N + 255)/256)      // 132
#define COUNT_BLKS  ((E_1 + E_2 + 255)/256)   // 157

typedef float f32x4 __attribute__((ext_vector_type(4)));
typedef short s16x8 __attribute__((ext_vector_type(8)));   // 8 bf16 = 4 VGPRs

__device__ __forceinline__ void load_lds16(const void* g, void* l) {
    __builtin_amdgcn_global_load_lds(
        (const __attribute__((address_space(1))) unsigned int*)g,
        (__attribute__((address_space(3))) unsigned int*)l, 16, 0, 0);
}

__device__ __forceinline__ s16x8 pack_bf16x8(float4 x, float4 y, float s) {
    union { s16x8 v; __hip_bfloat162 h[4]; } u;
    u.h[0] = __float22bfloat162_rn(make_float2(s * x.x, s * x.y));
    u.h[1] = __float22bfloat162_rn(make_float2(s * x.z, s * x.w));
    u.h[2] = __float22bfloat162_rn(make_float2(s * y.x, s * y.y));
    u.h[3] = __float22bfloat162_rn(make_float2(s * y.z, s * y.w));
    return u.v;
}

__device__ __forceinline__ unsigned short f2bf_rne(float f) {
    unsigned u = __float_as_uint(f);
    return (unsigned short)((u + 0x7FFFu + ((u >> 16) & 1u)) >> 16);
}

// Fused setup: blocks [0,132) convert W+b -> bf16 swizzled tables;
// blocks [132, 132+157) build per-dst slot tables + degrees.
// Wt layout: [chunk][n(o)][k8] 16B units, unit(n,k8) -> n*8 + (k8 ^ (n&7)).
__global__ __launch_bounds__(256) void setup_kernel(
    const float* __restrict__ W1, const float* __restrict__ b1,
    const float* __restrict__ W2, const float* __restrict__ b2,
    uint4* __restrict__ Wt1, uint4* __restrict__ Wt2,
    const int* __restrict__ dst1, const int* __restrict__ dst2,
    int* __restrict__ cur1, int* __restrict__ slots1,
    int* __restrict__ cur2, int* __restrict__ slots2)
{
    if (blockIdx.x < PREP_BLKS) {
        int gid = blockIdx.x * 256 + threadIdx.x;
        if (gid >= PREP_N) return;
        int layer = gid / (NCHUNK * 512);
        int r     = gid % (NCHUNK * 512);
        int c  = r / 512;
        int u  = r % 512;
        int k8 = u / 64;
        int n  = u % 64;
        const float* W = layer ? W2 : W1;
        const float* b = layer ? b2 : b1;
        const float* s = (c < 32) ? (W + (size_t)c * 4096) : b;
        union { uint4 v; unsigned short us[8]; } pk;
        #pragma unroll
        for (int j = 0; j < 8; ++j)
            pk.us[j] = f2bf_rne(s[(k8 * 8 + j) * 64 + n]);
        uint4* Wt = layer ? Wt2 : Wt1;
        Wt[(size_t)c * 512 + n * 8 + (k8 ^ (n & 7))] = pk.v;
    } else {
        int i = (blockIdx.x - PREP_BLKS) * 256 + threadIdx.x;
        if (i < E_1) {
            int d = dst1[i];
            int p = atomicAdd(&cur1[d], 1);
            if (p < MAXDEG) slots1[(size_t)d * MAXDEG + p] = i;
        } else if (i < E_1 + E_2) {
            int e = i - E_1;
            int d = dst2[e];
            int p = atomicAdd(&cur2[d], 1);
            if (p < MAXDEG) slots2[(size_t)d * MAXDEG + p] = e;
        }
    }
}

// Phase A: fused NNConv message GEMM (MFMA), per-split partial stores.
// msg[split][e][o] = sum_{c in split} ef[e,c] * (hs[e,:] @ Wc)   (c==32: bias, ef=1)
// 128 edges/block; wave w owns edges [w*32, w*32+32) as two 16-row M-tiles,
// so each B-frag ds_read_b128 feeds 2 MFMAs.
__global__ __launch_bounds__(256) void nnconv_mfma(
    const float* __restrict__ h,      // [n_rows, 64] fp32
    const float* __restrict__ efeat,  // [E, 32] fp32
    const uint4* __restrict__ Wt,     // [33][512] swizzled bf16 units
    const int*  __restrict__ src,
    int E,
    float* __restrict__ msg)          // [NSPLIT][EPAD][64]
{
    __shared__ float efs[7][EBLK];        // [c - c_lo][edge], split range <= 7 chunks
    __shared__ uint4 wbuf[2][512];        // double-buffered W chunk (8 KB each)

    const int t  = threadIdx.x;
    const int w  = t >> 6;                // wave 0..3
    const int l  = t & 63;
    const int m15 = l & 15;               // MFMA row (A) / col (B,C)
    const int q   = l >> 4;               // quad 0..3
    const int ebase = blockIdx.x * EBLK;
    const int split = blockIdx.y;
    const int c_lo = (split * 33) / NSPLIT;
    const int c_hi = ((split + 1) * 33) / NSPLIT;
    const int nc   = c_hi - c_lo;         // 6 or 7

    // ---- stage this split's edge-feature columns, f-major (bias col -> 1.0) ----
    for (int idx = t; idx < nc * EBLK; idx += 256) {
        int f = idx >> 7, e = idx & (EBLK - 1);
        int eg = ebase + e, c = c_lo + f;
        float v = 0.0f;
        if (eg < E) v = (c < 32) ? efeat[eg * 32 + c] : 1.0f;
        efs[f][e] = v;
    }

    // ---- issue first W chunk into wbuf[0] ----
    {
        const uint4* g = Wt + (size_t)c_lo * 512;
        load_lds16(g + t,       &wbuf[0][t]);
        load_lds16(g + 256 + t, &wbuf[0][256 + t]);
    }

    // ---- A-frag fp32 preload (gather, once per block): 2 M-tiles ----
    const int e0 = ebase + w * 32 + m15;
    const int e1 = e0 + 16;
    const int r0 = (e0 < E) ? src[e0] : 0;
    const int r1 = (e1 < E) ? src[e1] : 0;
    const float* hp0 = h + (size_t)r0 * 64 + q * 8;
    const float* hp1 = h + (size_t)r1 * 64 + q * 8;
    const float4 t0a0 = *(const float4*)(hp0);
    const float4 t0a1 = *(const float4*)(hp0 + 4);
    const float4 t0b0 = *(const float4*)(hp0 + 32);
    const float4 t0b1 = *(const float4*)(hp0 + 36);
    const float4 t1a0 = *(const float4*)(hp1);
    const float4 t1a1 = *(const float4*)(hp1 + 4);
    const float4 t1b0 = *(const float4*)(hp1 + 32);
    const float4 t1b1 = *(const float4*)(hp1 + 36);

    f32x4 acc0[4] = {};   // M-tile 0 x 4 N-tiles
    f32x4 acc1[4] = {};   // M-tile 1
    const int nx = m15 & 7;

    int cur = 0;
    for (int c = c_lo; c < c_hi; ++c) {
        __syncthreads();                          // wbuf[cur] resident; prev reads done
        if (c + 1 < c_hi) {
            const uint4* g = Wt + (size_t)(c + 1) * 512;
            load_lds16(g + t,       &wbuf[cur ^ 1][t]);
            load_lds16(g + 256 + t, &wbuf[cur ^ 1][256 + t]);
        }
        const float ef0 = efs[c - c_lo][w * 32 + m15];
        const float ef1 = efs[c - c_lo][w * 32 + 16 + m15];
        const s16x8 a00 = pack_bf16x8(t0a0, t0a1, ef0);   // tile0 k 0..31
        const s16x8 a01 = pack_bf16x8(t0b0, t0b1, ef0);   // tile0 k 32..63
        const s16x8 a10 = pack_bf16x8(t1a0, t1a1, ef1);   // tile1 k 0..31
        const s16x8 a11 = pack_bf16x8(t1b0, t1b1, ef1);   // tile1 k 32..63
        const uint4* wb = wbuf[cur];
        #pragma unroll
        for (int n16 = 0; n16 < 4; ++n16) {
            const int n = n16 * 16 + m15;
            const s16x8 b0 = *(const s16x8*)&wb[n * 8 + ((q)     ^ nx)];
            const s16x8 b1 = *(const s16x8*)&wb[n * 8 + ((4 + q) ^ nx)];
            acc0[n16] = __builtin_amdgcn_mfma_f32_16x16x32_bf16(a00, b0, acc0[n16], 0, 0, 0);
            acc0[n16] = __builtin_amdgcn_mfma_f32_16x16x32_bf16(a01, b1, acc0[n16], 0, 0, 0);
            acc1[n16] = __builtin_amdgcn_mfma_f32_16x16x32_bf16(a10, b0, acc1[n16], 0, 0, 0);
            acc1[n16] = __builtin_amdgcn_mfma_f32_16x16x32_bf16(a11, b1, acc1[n16], 0, 0, 0);
        }
        cur ^= 1;
    }

    // ---- plain stores: lane holds D[m=q*4+r][n=n16*16+m15] per tile ----
    float* mp = msg + (size_t)split * EPAD * 64;
    #pragma unroll
    for (int r = 0; r < 4; ++r) {
        float* rp0 = mp + (size_t)(ebase + w * 32 + q * 4 + r) * 64 + m15;
        float* rp1 = rp0 + 16 * 64;
        #pragma unroll
        for (int n16 = 0; n16 < 4; ++n16) {
            rp0[n16 * 16] = acc0[n16][r];
            rp1[n16 * 16] = acc1[n16][r];
        }
    }
}

// Phase B: one wave per dst node; lane = output col. Sum split partials over
// the dst's edge list, divide by degree, optional ReLU. No fp32 atomics.
__global__ __launch_bounds__(256) void gather_mean(
    const float* __restrict__ msg,   // [NSPLIT][EPAD][64]
    const int* __restrict__ slots, const int* __restrict__ cur,
    int n_dst, int do_relu, float* __restrict__ outp)
{
    int d = blockIdx.x * 4 + (threadIdx.x >> 6);
    int o = threadIdx.x & 63;
    if (d >= n_dst) return;
    int deg = cur[d];
    int dg = min(deg, MAXDEG);
    float s = 0.0f;
    for (int j = 0; j < dg; ++j) {
        int e = slots[(size_t)d * MAXDEG + j];     // wave-uniform -> broadcast
        const float* mrow = msg + (size_t)e * 64 + o;
        #pragma unroll
        for (int sp = 0; sp < NSPLIT; ++sp)
            s += mrow[(size_t)sp * EPAD * 64];
    }
    s *= 1.0f / fmaxf((float)deg, 1.0f);
    if (do_relu) s = fmaxf(s, 0.0f);
    outp[(size_t)d * 64 + o] = s;
}

extern "C" void kernel_launch(void* const* d_in, const int* in_sizes, int n_in,
                              void* d_out, int out_size, void* d_ws, size_t ws_size,
                              hipStream_t stream)
{
    const float* in_feat = (const float*)d_in[0];
    const float* ef1     = (const float*)d_in[1];
    const float* ef2     = (const float*)d_in[2];
    const float* W1      = (const float*)d_in[3];
    const float* b1      = (const float*)d_in[4];
    const float* W2      = (const float*)d_in[5];
    const float* b2      = (const float*)d_in[6];
    const int*   src1    = (const int*)d_in[7];
    const int*   dst1    = (const int*)d_in[8];
    const int*   src2    = (const int*)d_in[9];
    const int*   dst2    = (const int*)d_in[10];

    // Workspace layout (Wt offset 8,420,000 B and msg offset are 16B-aligned)
    float* h_mid  = (float*)d_ws;                        // [20000*64]
    int*   cur1   = (int*)(h_mid + (size_t)N_MID * 64);  // [20000]
    int*   cur2   = cur1 + N_MID;                        // [5000]
    int*   slots1 = cur2 + N_OUT;                        // [20000*32]
    int*   slots2 = slots1 + (size_t)N_MID * MAXDEG;     // [5000*32]
    uint4* Wt1    = (uint4*)(slots2 + (size_t)N_OUT * MAXDEG);
    uint4* Wt2    = Wt1 + (size_t)NCHUNK * 512;
    float* msg    = (float*)(Wt2 + (size_t)NCHUNK * 512);// [NSPLIT*EPAD*64]
    float* out    = (float*)d_out;                       // [5000*64]

    // only the cursors need zeroing (contiguous 25000 ints)
    hipMemsetAsync(cur1, 0, (size_t)(N_MID + N_OUT) * sizeof(int), stream);

    setup_kernel<<<PREP_BLKS + COUNT_BLKS, 256, 0, stream>>>(
        W1, b1, W2, b2, Wt1, Wt2, dst1, dst2, cur1, slots1, cur2, slots2);

    dim3 grid(NBLK, NSPLIT);
    nnconv_mfma<<<grid, 256, 0, stream>>>(in_feat, ef1, Wt1, src1, E_1, msg);
    gather_mean<<<(N_MID + 3) / 4, 256, 0, stream>>>(msg, slots1, cur1, N_MID, 1, h_mid);

    nnconv_mfma<<<grid, 256, 0, stream>>>(h_mid, ef2, Wt2, src2, E_2, msg);
    gather_mean<<<(N_OUT + 3) / 4, 256, 0, stream>>>(msg, slots2, cur2, N_OUT, 0, out);
}